// Round 1
// baseline (6296.768 us; speedup 1.0000x reference)
//
#include <hip/hip_runtime.h>
#include <stdint.h>

// LBG (Linde-Buzo-Gray) vector quantization, bit-faithful port of the JAX ref.
// x: (131072, 64) f32. K=256 codewords. 8 split levels x up to 5 Lloyd iters.
// Output: codebook (256*64 f32) then distance scalar -> 16385 floats in d_out.
// PRNG: threefry2x32, JAX *partitionable* mode (default since jax 0.4.36).
// All cross-block reductions use integer fixed-point atomics => deterministic
// across graph replays.

#define NPTS 131072
#define DIMS 64
#define KCB  256

struct LbgState { float dist; float prev; unsigned int done; unsigned int k0, k1; unsigned int pad; };

__device__ __forceinline__ uint32_t rotl32(uint32_t v, int n){ return (v<<n)|(v>>(32-n)); }

// Threefry-2x32, 20 rounds (matches jax._src.prng.threefry2x32)
__device__ __forceinline__ void tf2x32(uint32_t k0, uint32_t k1, uint32_t x0, uint32_t x1,
                                       uint32_t& o0, uint32_t& o1){
  uint32_t ks2 = k0 ^ k1 ^ 0x1BD11BDAu;
  x0 += k0; x1 += k1;
  #define TFR(r) { x0 += x1; x1 = rotl32(x1, r); x1 ^= x0; }
  TFR(13) TFR(15) TFR(26) TFR(6)
  x0 += k1; x1 += ks2 + 1u;
  TFR(17) TFR(29) TFR(16) TFR(24)
  x0 += ks2; x1 += k0 + 2u;
  TFR(13) TFR(15) TFR(26) TFR(6)
  x0 += k0; x1 += k1 + 3u;
  TFR(17) TFR(29) TFR(16) TFR(24)
  x0 += k1; x1 += ks2 + 4u;
  TFR(13) TFR(15) TFR(26) TFR(6)
  x0 += ks2; x1 += k0 + 5u;
  #undef TFR
  o0 = x0; o1 = x1;
}

// XLA ErfInv (f32, Giles polynomial) — what lax.erf_inv lowers to.
__device__ __forceinline__ float xla_erfinv_f32(float x){
  float w = -log1pf(-x*x);
  float p;
  if (w < 5.0f){
    w = w - 2.5f;
    p = 2.81022636e-08f;
    p = fmaf(p, w, 3.43273939e-07f);
    p = fmaf(p, w, -3.5233877e-06f);
    p = fmaf(p, w, -4.39150654e-06f);
    p = fmaf(p, w, 0.00021858087f);
    p = fmaf(p, w, -0.00125372503f);
    p = fmaf(p, w, -0.00417768164f);
    p = fmaf(p, w, 0.246640727f);
    p = fmaf(p, w, 1.50140941f);
  } else {
    w = sqrtf(w) - 3.0f;
    p = -0.000200214257f;
    p = fmaf(p, w, 0.000100950558f);
    p = fmaf(p, w, 0.00134934322f);
    p = fmaf(p, w, -0.00367342844f);
    p = fmaf(p, w, 0.00573950773f);
    p = fmaf(p, w, -0.0076224613f);
    p = fmaf(p, w, 0.00943887047f);
    p = fmaf(p, w, 1.00167406f);
    p = fmaf(p, w, 2.83297682f);
  }
  return p * x;
}

// element j of jax.random.normal(key, (n,)) with threefry_partitionable=True:
// bits_j = w0 ^ w1 of E_key(hi=0, lo=j); uniform in [nextafter(-1,0), 1); sqrt2*erfinv.
__device__ __forceinline__ float jax_normal_elem(uint32_t k0, uint32_t k1, uint32_t j){
  uint32_t o0, o1; tf2x32(k0, k1, 0u, j, o0, o1);
  uint32_t bits = o0 ^ o1;
  uint32_t fb = (bits >> 9) | 0x3f800000u;
  float f = __uint_as_float(fb) - 1.0f;      // [0,1)
  const float lo = -0.99999994f;             // nextafter(-1,0) f32
  float u = f * 2.0f + lo;                   // (hi-lo) rounds to exactly 2.0f
  u = fmaxf(lo, u);
  return 1.41421356f * xla_erfinv_f32(u);    // np.float32(np.sqrt(2)) = 0x3FB504F3
}

// --- mean of x over points (fixed-point 2^40 int64 atomics, deterministic) ---
__global__ void mean_kernel(const float* __restrict__ x, unsigned long long* __restrict__ macc){
  __shared__ double part[256];
  const int t = threadIdx.x;
  const int d = t & 63;
  const int w = t >> 6;
  const size_t base = (size_t)blockIdx.x * 1024;
  double s = 0.0;
  for (int j = w; j < 1024; j += 4)
    s += (double)x[(base + j) * DIMS + d];
  part[t] = s;
  __syncthreads();
  if (t < 64){
    double tot = part[t] + part[64+t] + part[128+t] + part[192+t];
    atomicAdd(&macc[t], (unsigned long long)__double2ll_rn(tot * 1099511627776.0));
  }
}

__global__ void init_kernel(float* __restrict__ cb, const unsigned long long* __restrict__ macc,
                            LbgState* __restrict__ st){
  const int t = threadIdx.x;
  for (int e = t; e < KCB*DIMS; e += 256){
    int c = e >> 6, d = e & 63;
    float v;
    if (c == 0){
      double mean = (double)(long long)macc[d] * (1.0/1099511627776.0) / 131072.0;
      v = (float)mean;
    } else v = 1e10f;
    cb[e] = v;
  }
  if (t == 0){
    st->dist = __builtin_inff();
    st->prev = __builtin_inff();
    st->done = 0u;
  }
}

// --- split level: fold_in(base,split) -> (kr, kloop); perturb codebook, reset state ---
__global__ void split_kernel(float* __restrict__ cb, float* __restrict__ cnorm,
                             unsigned long long* __restrict__ sums,
                             unsigned int* __restrict__ ndata,
                             unsigned long long* __restrict__ distacc,
                             LbgState* __restrict__ st, int curr, int split){
  __shared__ uint32_t kr0, kr1;
  const int t = threadIdx.x;
  if (t == 0){
    uint32_t ks0, ks1;
    tf2x32(0u, 42u, 0u, (uint32_t)split, ks0, ks1);    // fold_in(key(42), split)
    uint32_t a0, a1, b0, b1;
    tf2x32(ks0, ks1, 0u, 0u, a0, a1);                  // split()[0] = kr
    tf2x32(ks0, ks1, 0u, 1u, b0, b1);                  // split()[1] = kloop
    kr0 = a0; kr1 = a1;
    st->k0 = b0; st->k1 = b1;
    st->prev = st->dist;
    st->done = 0u;
  }
  __syncthreads();
  const int n = curr * DIMS;
  for (int e = t; e < n; e += 256){
    int c = e >> 6, d = e & 63;
    float rv = jax_normal_elem(kr0, kr1, (uint32_t)e) * 1e-5f;
    float old = cb[c*DIMS + d];
    cb[(curr + c)*DIMS + d] = old - rv;
    cb[c*DIMS + d]          = old + rv;
  }
  __syncthreads();
  const int c2 = curr * 2;
  for (int c = t; c < c2; c += 256){
    float s = 0.f;
    for (int d = 0; d < DIMS; d++){ float vv = cb[c*DIMS+d]; s += vv*vv; }
    cnorm[c] = s;
  }
  for (int e = t; e < c2*DIMS; e += 256) sums[e] = 0ull;
  for (int c = t; c < c2; c += 256) ndata[c] = 0u;
  if (t == 0) *distacc = 0ull;
}

// --- E-step + M-step accumulation (fused). One thread per point. ---
// sums: int64 fixed-point 2^40 (via LDS int32 bins at 2^20, replicated R-way for
// small curr to cut LDS-atomic same-address conflicts). dist: int64 @ 2^32 via
// per-wave deterministic shuffle-reduce.
template<int CURR>
__global__ void assign_kernel(const float* __restrict__ x, const float* __restrict__ cb,
                              const float* __restrict__ cnorm,
                              unsigned long long* __restrict__ sums,
                              unsigned int* __restrict__ ndata,
                              unsigned long long* __restrict__ distacc,
                              const LbgState* __restrict__ st){
  if (st->done) return;
  constexpr int R = (CURR <= 16) ? 8 : ((CURR <= 64) ? 2 : 1);
  constexpr bool CNT_LDS = (CURR <= 128);
  __shared__ int sbin[R*CURR*DIMS];                 // <= 64 KB (CURR=256,R=1)
  __shared__ unsigned int scnt[CNT_LDS ? R*CURR : 1];
  const int t = threadIdx.x;
  for (int e = t; e < R*CURR*DIMS; e += 256) sbin[e] = 0;
  if (CNT_LDS) for (int c = t; c < R*CURR; c += 256) scnt[c] = 0u;
  __syncthreads();

  const int p = blockIdx.x * 256 + t;
  float xv[DIMS];
  const float4* xp = reinterpret_cast<const float4*>(x + (size_t)p * DIMS);
  #pragma unroll
  for (int i = 0; i < 16; i++){
    float4 v = xp[i];
    xv[4*i+0] = v.x; xv[4*i+1] = v.y; xv[4*i+2] = v.z; xv[4*i+3] = v.w;
  }
  float xx = 0.f;
  #pragma unroll
  for (int d = 0; d < DIMS; d++) xx += xv[d] * xv[d];

  constexpr int NJ = (CURR < 4) ? CURR : 4;
  float best = __builtin_inff();
  int bidx = 0;
  for (int j0 = 0; j0 < CURR; j0 += NJ){
    float acc[NJ];
    #pragma unroll
    for (int k2 = 0; k2 < NJ; k2++) acc[k2] = 0.f;
    #pragma unroll
    for (int d = 0; d < DIMS; d++){
      #pragma unroll
      for (int k2 = 0; k2 < NJ; k2++)
        acc[k2] = fmaf(xv[d], cb[(j0+k2)*DIMS + d], acc[k2]);  // uniform addr -> s_load
    }
    #pragma unroll
    for (int k2 = 0; k2 < NJ; k2++){
      float d2 = (xx - 2.0f*acc[k2]) + cnorm[j0+k2];           // ref rounding order
      if (d2 < best){ best = d2; bidx = j0+k2; }               // first-min like argmin
    }
  }

  // dist contribution: recompute sum((x - cb[idx])^2) like the reference
  double dd = 0.0;
  #pragma unroll
  for (int d = 0; d < DIMS; d++){
    float df = xv[d] - cb[bidx*DIMS + d];
    float sq = df * df;
    dd += (double)sq;
  }
  // deterministic in-wave reduce then one integer atomic per wave
  for (int off = 32; off > 0; off >>= 1) dd += __shfl_down(dd, off);
  if ((t & 63) == 0)
    atomicAdd(distacc, (unsigned long long)__double2ll_rn(dd * 4294967296.0));

  // segment-sum accumulation (int32 @ 2^20 in LDS)
  const int rep = t & (R - 1);
  int* mybin = &sbin[(rep*CURR + bidx)*DIMS];
  #pragma unroll
  for (int d = 0; d < DIMS; d++){
    int iv = __double2int_rn((double)xv[d] * 1048576.0);
    atomicAdd(&mybin[d], iv);
  }
  if (CNT_LDS) atomicAdd(&scnt[rep*CURR + bidx], 1u);
  else         atomicAdd(&ndata[bidx], 1u);

  __syncthreads();
  for (int e = t; e < R*CURR*DIMS; e += 256){
    int v = sbin[e];
    if (v) atomicAdd(&sums[e & (CURR*DIMS - 1)],
                     (unsigned long long)((long long)v * 1048576ll));  // 2^20 -> 2^40
  }
  if (CNT_LDS)
    for (int c = t; c < R*CURR; c += 256){
      unsigned int v = scnt[c];
      if (v) atomicAdd(&ndata[c & (CURR - 1)], v);
    }
}

// --- convergence + M-step finalize (one block). Mirrors scan-body semantics. ---
__global__ void control_kernel(float* __restrict__ cb, float* __restrict__ cnorm,
                               unsigned long long* __restrict__ sums,
                               unsigned int* __restrict__ ndata,
                               unsigned long long* __restrict__ distacc,
                               LbgState* __restrict__ st, int curr, int n_iter){
  if (st->done) return;
  __shared__ int s_stop;
  __shared__ uint32_t sub0, sub1;
  __shared__ float cm[64];
  __shared__ int redv[256];
  __shared__ int redi[256];
  __shared__ int s_m, s_cnt;
  const int t = threadIdx.x;
  if (t == 0){
    double dd = (double)(long long)(*distacc) * (1.0/4294967296.0);
    float sf = (float)dd;
    float d_new = sf / 131072.0f;                 // sum((x-xq)^2) / T
    float change = fabsf(st->prev - d_new);
    int conv = (n_iter > 0) && (change / (d_new + 1e-16f) < 1e-5f);
    st->dist = d_new;                             // dist_out = where(done, dist, d_new); done==0 here
    if (!conv) st->prev = d_new;                  // prev_out = where(stop, prev, d_new)
    st->done = conv ? 1u : 0u;
    s_stop = conv;
    if (!conv){
      uint32_t a0, a1, b0, b1;
      tf2x32(st->k0, st->k1, 0u, 0u, a0, a1);     // key, sub = split(key)
      tf2x32(st->k0, st->k1, 0u, 1u, b0, b1);
      st->k0 = a0; st->k1 = a1;
      sub0 = b0; sub1 = b1;
    }
  }
  __syncthreads();
  if (s_stop) return;                              // cb frozen

  // m = argmax(n_data), first max on ties
  int v = (t < curr) ? (int)ndata[t] : -1;
  redv[t] = v; redi[t] = t;
  __syncthreads();
  for (int s = 128; s > 0; s >>= 1){
    if (t < s){
      if (redv[t+s] > redv[t] || (redv[t+s] == redv[t] && redi[t+s] < redi[t])){
        redv[t] = redv[t+s]; redi[t] = redi[t+s];
      }
    }
    __syncthreads();
  }
  if (t == 0) s_m = redi[0];
  __syncthreads();
  redv[t] = (t < curr && ndata[t] == 0u) ? 1 : 0;
  __syncthreads();
  for (int s = 128; s > 0; s >>= 1){
    if (t < s) redv[t] += redv[t+s];
    __syncthreads();
  }
  if (t == 0) s_cnt = redv[0];
  __syncthreads();
  const int m = s_m;
  const int cntE = s_cnt;

  if (t < 64){
    unsigned int nm_ = ndata[m]; if (nm_ < 1u) nm_ = 1u;
    double cd = (double)(long long)sums[m*DIMS + t] * (1.0/1099511627776.0) / (double)nm_;
    cm[t] = (float)cd;
  }
  __syncthreads();

  const int total = curr * DIMS;
  for (int e = t; e < total; e += 256){
    int c = e >> 6, d = e & 63;
    if (c == m) continue;                          // row m written below (with corr)
    float nv;
    unsigned int nd = ndata[c];
    if (nd >= 1u){
      double cd = (double)(long long)sums[e] * (1.0/1099511627776.0) / (double)nd;
      nv = (float)cd;
    } else {
      float rv = jax_normal_elem(sub0, sub1, (uint32_t)e) * 1e-5f;
      nv = cm[d] - rv;
    }
    cb[e] = nv;
  }
  if (t < 64){
    float add = 0.f;
    if (cntE > 0){
      float acc = 0.f;
      for (int c = 0; c < curr; c++){
        if (ndata[c] == 0u)
          acc += jax_normal_elem(sub0, sub1, (uint32_t)(c*DIMS + t)) * 1e-5f;
      }
      add = acc / fmaxf((float)cntE, 1.0f);
    }
    cb[m*DIMS + t] = cm[t] + add;                  // new[m] = cent[m] + where(cnt>0, corr, 0)
  }
  __syncthreads();

  for (int c = t; c < curr; c += 256){
    float s = 0.f;
    for (int d = 0; d < DIMS; d++){ float vv = cb[c*DIMS+d]; s += vv*vv; }
    cnorm[c] = s;
  }
  // zero accumulators for next iteration
  for (int e = t; e < total; e += 256) sums[e] = 0ull;
  for (int c = t; c < curr; c += 256) ndata[c] = 0u;
  if (t == 0) *distacc = 0ull;
}

__global__ void finalize_kernel(float* __restrict__ out, const LbgState* __restrict__ st){
  out[KCB*DIMS] = st->dist;
}

extern "C" void kernel_launch(void* const* d_in, const int* in_sizes, int n_in,
                              void* d_out, int out_size, void* d_ws, size_t ws_size,
                              hipStream_t stream){
  const float* x = (const float*)d_in[0];
  float* out = (float*)d_out;
  float* cb = out;                                  // codebook lives in d_out[0:16384]
  char* ws = (char*)d_ws;
  unsigned long long* sums    = (unsigned long long*)(ws + 0);       // 256*64*8 = 131072
  unsigned long long* macc    = (unsigned long long*)(ws + 131072);  // 64*8 = 512
  unsigned long long* distacc = (unsigned long long*)(ws + 131584);  // 8
  LbgState* st                = (LbgState*)(ws + 131592);            // 24
  unsigned int* ndata         = (unsigned int*)(ws + 131616);        // 256*4 = 1024
  float* cnorm                = (float*)(ws + 132640);               // 256*4 = 1024 -> 133664 total

  hipMemsetAsync(d_ws, 0, 133664, stream);
  mean_kernel<<<128, 256, 0, stream>>>(x, macc);
  init_kernel<<<1, 256, 0, stream>>>(cb, macc, st);

  int curr = 1;
  for (int split = 0; split < 8; split++){
    split_kernel<<<1, 256, 0, stream>>>(cb, cnorm, sums, ndata, distacc, st, curr, split);
    curr *= 2;
    for (int n = 0; n < 5; n++){
      switch (curr){
        case 2:   assign_kernel<2>  <<<512,256,0,stream>>>(x,cb,cnorm,sums,ndata,distacc,st); break;
        case 4:   assign_kernel<4>  <<<512,256,0,stream>>>(x,cb,cnorm,sums,ndata,distacc,st); break;
        case 8:   assign_kernel<8>  <<<512,256,0,stream>>>(x,cb,cnorm,sums,ndata,distacc,st); break;
        case 16:  assign_kernel<16> <<<512,256,0,stream>>>(x,cb,cnorm,sums,ndata,distacc,st); break;
        case 32:  assign_kernel<32> <<<512,256,0,stream>>>(x,cb,cnorm,sums,ndata,distacc,st); break;
        case 64:  assign_kernel<64> <<<512,256,0,stream>>>(x,cb,cnorm,sums,ndata,distacc,st); break;
        case 128: assign_kernel<128><<<512,256,0,stream>>>(x,cb,cnorm,sums,ndata,distacc,st); break;
        case 256: assign_kernel<256><<<512,256,0,stream>>>(x,cb,cnorm,sums,ndata,distacc,st); break;
      }
      control_kernel<<<1, 256, 0, stream>>>(cb, cnorm, sums, ndata, distacc, st, curr, n);
    }
  }
  finalize_kernel<<<1, 1, 0, stream>>>(out, st);
}

// Round 2
// 5304.798 us; speedup vs baseline: 1.1870x; 1.1870x over previous
//
#include <hip/hip_runtime.h>
#include <stdint.h>

// LBG vector quantization, bit-faithful port of the JAX ref.
// Round 2: split E-step (compute-bound, high occupancy, wave-uniform cb access)
// from scatter (LDS-atomic-bound, transposed bins). Trajectory-identical
// arithmetic to round 1 (which passed at absmax 0.59 / thr 1.115).

#define NPTS 131072
#define DIMS 64
#define KCB  256

struct LbgState { float dist; float prev; unsigned int done; unsigned int k0, k1; unsigned int pad; };

__device__ __forceinline__ uint32_t rotl32(uint32_t v, int n){ return (v<<n)|(v>>(32-n)); }

// Threefry-2x32, 20 rounds (matches jax._src.prng.threefry2x32)
__device__ __forceinline__ void tf2x32(uint32_t k0, uint32_t k1, uint32_t x0, uint32_t x1,
                                       uint32_t& o0, uint32_t& o1){
  uint32_t ks2 = k0 ^ k1 ^ 0x1BD11BDAu;
  x0 += k0; x1 += k1;
  #define TFR(r) { x0 += x1; x1 = rotl32(x1, r); x1 ^= x0; }
  TFR(13) TFR(15) TFR(26) TFR(6)
  x0 += k1; x1 += ks2 + 1u;
  TFR(17) TFR(29) TFR(16) TFR(24)
  x0 += ks2; x1 += k0 + 2u;
  TFR(13) TFR(15) TFR(26) TFR(6)
  x0 += k0; x1 += k1 + 3u;
  TFR(17) TFR(29) TFR(16) TFR(24)
  x0 += k1; x1 += ks2 + 4u;
  TFR(13) TFR(15) TFR(26) TFR(6)
  x0 += ks2; x1 += k0 + 5u;
  #undef TFR
  o0 = x0; o1 = x1;
}

// XLA ErfInv (f32, Giles polynomial)
__device__ __forceinline__ float xla_erfinv_f32(float x){
  float w = -log1pf(-x*x);
  float p;
  if (w < 5.0f){
    w = w - 2.5f;
    p = 2.81022636e-08f;
    p = fmaf(p, w, 3.43273939e-07f);
    p = fmaf(p, w, -3.5233877e-06f);
    p = fmaf(p, w, -4.39150654e-06f);
    p = fmaf(p, w, 0.00021858087f);
    p = fmaf(p, w, -0.00125372503f);
    p = fmaf(p, w, -0.00417768164f);
    p = fmaf(p, w, 0.246640727f);
    p = fmaf(p, w, 1.50140941f);
  } else {
    w = sqrtf(w) - 3.0f;
    p = -0.000200214257f;
    p = fmaf(p, w, 0.000100950558f);
    p = fmaf(p, w, 0.00134934322f);
    p = fmaf(p, w, -0.00367342844f);
    p = fmaf(p, w, 0.00573950773f);
    p = fmaf(p, w, -0.0076224613f);
    p = fmaf(p, w, 0.00943887047f);
    p = fmaf(p, w, 1.00167406f);
    p = fmaf(p, w, 2.83297682f);
  }
  return p * x;
}

__device__ __forceinline__ float jax_normal_elem(uint32_t k0, uint32_t k1, uint32_t j){
  uint32_t o0, o1; tf2x32(k0, k1, 0u, j, o0, o1);
  uint32_t bits = o0 ^ o1;
  uint32_t fb = (bits >> 9) | 0x3f800000u;
  float f = __uint_as_float(fb) - 1.0f;
  const float lo = -0.99999994f;
  float u = f * 2.0f + lo;
  u = fmaxf(lo, u);
  return 1.41421356f * xla_erfinv_f32(u);
}

// --- mean of x (fixed-point 2^40 int64 atomics, deterministic) ---
__global__ void mean_kernel(const float* __restrict__ x, unsigned long long* __restrict__ macc){
  __shared__ double part[256];
  const int t = threadIdx.x;
  const int d = t & 63;
  const int w = t >> 6;
  const size_t base = (size_t)blockIdx.x * 1024;
  double s = 0.0;
  for (int j = w; j < 1024; j += 4)
    s += (double)x[(base + j) * DIMS + d];
  part[t] = s;
  __syncthreads();
  if (t < 64){
    double tot = part[t] + part[64+t] + part[128+t] + part[192+t];
    atomicAdd(&macc[t], (unsigned long long)__double2ll_rn(tot * 1099511627776.0));
  }
}

__global__ void init_kernel(float* __restrict__ cb, const unsigned long long* __restrict__ macc,
                            LbgState* __restrict__ st){
  const int t = threadIdx.x;
  for (int e = t; e < KCB*DIMS; e += 256){
    int c = e >> 6, d = e & 63;
    float v;
    if (c == 0){
      double mean = (double)(long long)macc[d] * (1.0/1099511627776.0) / 131072.0;
      v = (float)mean;
    } else v = 1e10f;
    cb[e] = v;
  }
  if (t == 0){
    st->dist = __builtin_inff();
    st->prev = __builtin_inff();
    st->done = 0u;
  }
}

// --- split level ---
__global__ void split_kernel(float* __restrict__ cb, float* __restrict__ cnorm,
                             unsigned long long* __restrict__ sums,
                             unsigned int* __restrict__ ndata,
                             unsigned long long* __restrict__ distacc,
                             LbgState* __restrict__ st, int curr, int split){
  __shared__ uint32_t kr0, kr1;
  const int t = threadIdx.x;
  if (t == 0){
    uint32_t ks0, ks1;
    tf2x32(0u, 42u, 0u, (uint32_t)split, ks0, ks1);
    uint32_t a0, a1, b0, b1;
    tf2x32(ks0, ks1, 0u, 0u, a0, a1);
    tf2x32(ks0, ks1, 0u, 1u, b0, b1);
    kr0 = a0; kr1 = a1;
    st->k0 = b0; st->k1 = b1;
    st->prev = st->dist;
    st->done = 0u;
  }
  __syncthreads();
  const int n = curr * DIMS;
  for (int e = t; e < n; e += 256){
    int c = e >> 6, d = e & 63;
    float rv = jax_normal_elem(kr0, kr1, (uint32_t)e) * 1e-5f;
    float old = cb[c*DIMS + d];
    cb[(curr + c)*DIMS + d] = old - rv;
    cb[c*DIMS + d]          = old + rv;
  }
  __syncthreads();
  const int c2 = curr * 2;
  for (int c = t; c < c2; c += 256){
    float s = 0.f;
    for (int d = 0; d < DIMS; d++){ float vv = cb[c*DIMS+d]; s += vv*vv; }
    cnorm[c] = s;
  }
  for (int e = t; e < c2*DIMS; e += 256) sums[e] = 0ull;
  for (int c = t; c < c2; c += 256) ndata[c] = 0u;
  if (t == 0) *distacc = 0ull;
}

// --- E-step: block = 64 points x 4 waves; wave w scans a uniform cw-slice. ---
// cb access is wave-uniform (scalar-load path, 64x reuse). Combine via 2 KB LDS
// preserving first-min order; dist recomputed with round-1-identical rounding.
template<int CURR>
__global__ __launch_bounds__(256, 4)
void estep_kernel(const float* __restrict__ x, const float* __restrict__ cb,
                  const float* __restrict__ cnorm, unsigned char* __restrict__ bidx8,
                  unsigned long long* __restrict__ distacc, const LbgState* __restrict__ st){
  if (st->done) return;
  constexpr int SPLITW = (CURR < 4) ? CURR : 4;
  constexpr int CW = CURR / SPLITW;            // codewords per wave
  __shared__ float sbest[SPLITW*64];
  __shared__ int   sidx [SPLITW*64];
  const int t = threadIdx.x;
  const int lane = t & 63;
  const int w = __builtin_amdgcn_readfirstlane(t >> 6);
  const int p = blockIdx.x * 64 + lane;

  float xv[DIMS];
  float xx = 0.f;
  if (w < SPLITW){
    const float4* xp = reinterpret_cast<const float4*>(x + (size_t)p * DIMS);
    #pragma unroll
    for (int i = 0; i < 16; i++){
      float4 v = xp[i];
      xv[4*i+0] = v.x; xv[4*i+1] = v.y; xv[4*i+2] = v.z; xv[4*i+3] = v.w;
    }
    #pragma unroll
    for (int d = 0; d < DIMS; d++) xx += xv[d] * xv[d];

    const int cbase = w * CW;
    constexpr int NJ = (CW < 4) ? CW : 4;
    float best = __builtin_inff();
    int bloc = 0;
    for (int j0 = 0; j0 < CW; j0 += NJ){
      const float* crow = cb + (size_t)(cbase + j0) * DIMS;
      float acc[NJ];
      #pragma unroll
      for (int k2 = 0; k2 < NJ; k2++) acc[k2] = 0.f;
      #pragma unroll
      for (int d = 0; d < DIMS; d++){
        #pragma unroll
        for (int k2 = 0; k2 < NJ; k2++)
          acc[k2] = fmaf(xv[d], crow[k2*DIMS + d], acc[k2]);
      }
      #pragma unroll
      for (int k2 = 0; k2 < NJ; k2++){
        float d2 = (xx - 2.0f*acc[k2]) + cnorm[cbase + j0 + k2];  // ref rounding order
        if (d2 < best){ best = d2; bloc = cbase + j0 + k2; }      // strict < = first-min
      }
    }
    sbest[w*64 + lane] = best;
    sidx [w*64 + lane] = bloc;
  }
  __syncthreads();
  if (w == 0){
    float best = sbest[lane];
    int bi = sidx[lane];
    #pragma unroll
    for (int ww = 1; ww < SPLITW; ww++){
      float ob = sbest[ww*64 + lane];
      int   oi = sidx [ww*64 + lane];
      if (ob < best){ best = ob; bi = oi; }   // ranges ascending -> ties keep lowest idx
    }
    bidx8[p] = (unsigned char)bi;
    // dist contribution: recompute sum((x-cb[bi])^2), same per-element rounding as R1
    double dd = 0.0;
    const float4* cbv = reinterpret_cast<const float4*>(cb + (size_t)bi * DIMS);
    #pragma unroll
    for (int i = 0; i < 16; i++){
      float4 b = cbv[i];
      float df, sq;
      df = xv[4*i+0] - b.x; sq = df*df; dd += (double)sq;
      df = xv[4*i+1] - b.y; sq = df*df; dd += (double)sq;
      df = xv[4*i+2] - b.z; sq = df*df; dd += (double)sq;
      df = xv[4*i+3] - b.w; sq = df*df; dd += (double)sq;
    }
    for (int off = 32; off > 0; off >>= 1) dd += __shfl_down(dd, off);
    if (lane == 0)
      atomicAdd(distacc, (unsigned long long)__double2ll_rn(dd * 4294967296.0));
  }
}

// --- Scatter: transposed bins [d*BINS + c*R + rep] (bank-conflict-free),
// replica pre-reduction before the u64 global flush. 512 threads, 1 pt/thread.
template<int CURR>
__global__ __launch_bounds__(512)
void scatter_kernel(const float* __restrict__ x, const unsigned char* __restrict__ bidx8,
                    unsigned long long* __restrict__ sums, unsigned int* __restrict__ ndata,
                    const LbgState* __restrict__ st){
  if (st->done) return;
  constexpr int R    = (CURR >= 64) ? 1 : (64 / CURR);
  constexpr int BINS = CURR * R;               // >= 64 for CURR <= 64
  constexpr int CLOG = __builtin_ctz(CURR);
  __shared__ int sbin[BINS*DIMS];
  __shared__ unsigned int scnt[BINS];
  const int t = threadIdx.x;
  for (int e = t; e < BINS*DIMS; e += 512) sbin[e] = 0;
  for (int c = t; c < BINS; c += 512) scnt[c] = 0u;
  __syncthreads();

  const int p = blockIdx.x * 512 + t;
  const int bi = (int)bidx8[p];
  const int col = bi * R + (t & (R - 1));
  const float4* xp = reinterpret_cast<const float4*>(x + (size_t)p * DIMS);
  #pragma unroll
  for (int i = 0; i < 16; i++){
    float4 v = xp[i];
    atomicAdd(&sbin[(4*i+0)*BINS + col], __double2int_rn((double)v.x * 1048576.0));
    atomicAdd(&sbin[(4*i+1)*BINS + col], __double2int_rn((double)v.y * 1048576.0));
    atomicAdd(&sbin[(4*i+2)*BINS + col], __double2int_rn((double)v.z * 1048576.0));
    atomicAdd(&sbin[(4*i+3)*BINS + col], __double2int_rn((double)v.w * 1048576.0));
  }
  atomicAdd(&scnt[col], 1u);
  __syncthreads();

  // flush: e = d*CURR + c (consecutive lanes -> consecutive c -> spread banks)
  for (int e = t; e < CURR*DIMS; e += 512){
    const int c = e & (CURR - 1);
    const int d = e >> CLOG;
    long long v = 0;
    #pragma unroll
    for (int rep = 0; rep < R; rep++) v += (long long)sbin[d*BINS + c*R + rep];
    if (v) atomicAdd(&sums[c*DIMS + d], (unsigned long long)(v * 1048576ll)); // 2^20 -> 2^40
  }
  for (int c = t; c < CURR; c += 512){
    unsigned int v = 0;
    #pragma unroll
    for (int rep = 0; rep < R; rep++) v += scnt[c*R + rep];
    if (v) atomicAdd(&ndata[c], v);
  }
}

// --- convergence + M-step finalize (one block) ---
__global__ void control_kernel(float* __restrict__ cb, float* __restrict__ cnorm,
                               unsigned long long* __restrict__ sums,
                               unsigned int* __restrict__ ndata,
                               unsigned long long* __restrict__ distacc,
                               LbgState* __restrict__ st, int curr, int n_iter){
  if (st->done) return;
  __shared__ int s_stop;
  __shared__ uint32_t sub0, sub1;
  __shared__ float cm[64];
  __shared__ int redv[256];
  __shared__ int redi[256];
  __shared__ int s_m, s_cnt;
  const int t = threadIdx.x;
  if (t == 0){
    double dd = (double)(long long)(*distacc) * (1.0/4294967296.0);
    float sf = (float)dd;
    float d_new = sf / 131072.0f;
    float change = fabsf(st->prev - d_new);
    int conv = (n_iter > 0) && (change / (d_new + 1e-16f) < 1e-5f);
    st->dist = d_new;
    if (!conv) st->prev = d_new;
    st->done = conv ? 1u : 0u;
    s_stop = conv;
    if (!conv){
      uint32_t a0, a1, b0, b1;
      tf2x32(st->k0, st->k1, 0u, 0u, a0, a1);
      tf2x32(st->k0, st->k1, 0u, 1u, b0, b1);
      st->k0 = a0; st->k1 = a1;
      sub0 = b0; sub1 = b1;
    }
  }
  __syncthreads();
  if (s_stop) return;

  int v = (t < curr) ? (int)ndata[t] : -1;
  redv[t] = v; redi[t] = t;
  __syncthreads();
  for (int s = 128; s > 0; s >>= 1){
    if (t < s){
      if (redv[t+s] > redv[t] || (redv[t+s] == redv[t] && redi[t+s] < redi[t])){
        redv[t] = redv[t+s]; redi[t] = redi[t+s];
      }
    }
    __syncthreads();
  }
  if (t == 0) s_m = redi[0];
  __syncthreads();
  redv[t] = (t < curr && ndata[t] == 0u) ? 1 : 0;
  __syncthreads();
  for (int s = 128; s > 0; s >>= 1){
    if (t < s) redv[t] += redv[t+s];
    __syncthreads();
  }
  if (t == 0) s_cnt = redv[0];
  __syncthreads();
  const int m = s_m;
  const int cntE = s_cnt;

  if (t < 64){
    unsigned int nm_ = ndata[m]; if (nm_ < 1u) nm_ = 1u;
    double cd = (double)(long long)sums[m*DIMS + t] * (1.0/1099511627776.0) / (double)nm_;
    cm[t] = (float)cd;
  }
  __syncthreads();

  const int total = curr * DIMS;
  for (int e = t; e < total; e += 256){
    int c = e >> 6, d = e & 63;
    if (c == m) continue;
    float nv;
    unsigned int nd = ndata[c];
    if (nd >= 1u){
      double cd = (double)(long long)sums[e] * (1.0/1099511627776.0) / (double)nd;
      nv = (float)cd;
    } else {
      float rv = jax_normal_elem(sub0, sub1, (uint32_t)e) * 1e-5f;
      nv = cm[d] - rv;
    }
    cb[e] = nv;
  }
  if (t < 64){
    float add = 0.f;
    if (cntE > 0){
      float acc = 0.f;
      for (int c = 0; c < curr; c++){
        if (ndata[c] == 0u)
          acc += jax_normal_elem(sub0, sub1, (uint32_t)(c*DIMS + t)) * 1e-5f;
      }
      add = acc / fmaxf((float)cntE, 1.0f);
    }
    cb[m*DIMS + t] = cm[t] + add;
  }
  __syncthreads();

  for (int c = t; c < curr; c += 256){
    float s = 0.f;
    for (int d = 0; d < DIMS; d++){ float vv = cb[c*DIMS+d]; s += vv*vv; }
    cnorm[c] = s;
  }
  for (int e = t; e < total; e += 256) sums[e] = 0ull;
  for (int c = t; c < curr; c += 256) ndata[c] = 0u;
  if (t == 0) *distacc = 0ull;
}

__global__ void finalize_kernel(float* __restrict__ out, const LbgState* __restrict__ st){
  out[KCB*DIMS] = st->dist;
}

extern "C" void kernel_launch(void* const* d_in, const int* in_sizes, int n_in,
                              void* d_out, int out_size, void* d_ws, size_t ws_size,
                              hipStream_t stream){
  const float* x = (const float*)d_in[0];
  float* out = (float*)d_out;
  float* cb = out;
  char* ws = (char*)d_ws;
  unsigned long long* sums    = (unsigned long long*)(ws + 0);       // 131072 B
  unsigned long long* macc    = (unsigned long long*)(ws + 131072);  // 512 B
  unsigned long long* distacc = (unsigned long long*)(ws + 131584);  // 8 B
  LbgState* st                = (LbgState*)(ws + 131592);            // 24 B
  unsigned int* ndata         = (unsigned int*)(ws + 131616);        // 1024 B
  float* cnorm                = (float*)(ws + 132640);               // 1024 B
  unsigned char* bidx8        = (unsigned char*)(ws + 133664);       // 131072 B -> 264736 total

  hipMemsetAsync(d_ws, 0, 264736, stream);
  mean_kernel<<<128, 256, 0, stream>>>(x, macc);
  init_kernel<<<1, 256, 0, stream>>>(cb, macc, st);

  int curr = 1;
  for (int split = 0; split < 8; split++){
    split_kernel<<<1, 256, 0, stream>>>(cb, cnorm, sums, ndata, distacc, st, curr, split);
    curr *= 2;
    for (int n = 0; n < 5; n++){
      switch (curr){
        case 2:   estep_kernel<2>  <<<2048,256,0,stream>>>(x,cb,cnorm,bidx8,distacc,st);
                  scatter_kernel<2>  <<<256,512,0,stream>>>(x,bidx8,sums,ndata,st); break;
        case 4:   estep_kernel<4>  <<<2048,256,0,stream>>>(x,cb,cnorm,bidx8,distacc,st);
                  scatter_kernel<4>  <<<256,512,0,stream>>>(x,bidx8,sums,ndata,st); break;
        case 8:   estep_kernel<8>  <<<2048,256,0,stream>>>(x,cb,cnorm,bidx8,distacc,st);
                  scatter_kernel<8>  <<<256,512,0,stream>>>(x,bidx8,sums,ndata,st); break;
        case 16:  estep_kernel<16> <<<2048,256,0,stream>>>(x,cb,cnorm,bidx8,distacc,st);
                  scatter_kernel<16> <<<256,512,0,stream>>>(x,bidx8,sums,ndata,st); break;
        case 32:  estep_kernel<32> <<<2048,256,0,stream>>>(x,cb,cnorm,bidx8,distacc,st);
                  scatter_kernel<32> <<<256,512,0,stream>>>(x,bidx8,sums,ndata,st); break;
        case 64:  estep_kernel<64> <<<2048,256,0,stream>>>(x,cb,cnorm,bidx8,distacc,st);
                  scatter_kernel<64> <<<256,512,0,stream>>>(x,bidx8,sums,ndata,st); break;
        case 128: estep_kernel<128><<<2048,256,0,stream>>>(x,cb,cnorm,bidx8,distacc,st);
                  scatter_kernel<128><<<256,512,0,stream>>>(x,bidx8,sums,ndata,st); break;
        case 256: estep_kernel<256><<<2048,256,0,stream>>>(x,cb,cnorm,bidx8,distacc,st);
                  scatter_kernel<256><<<256,512,0,stream>>>(x,bidx8,sums,ndata,st); break;
      }
      control_kernel<<<1, 256, 0, stream>>>(cb, cnorm, sums, ndata, distacc, st, curr, n);
    }
  }
  finalize_kernel<<<1, 1, 0, stream>>>(out, st);
}

// Round 3
// 4011.768 us; speedup vs baseline: 1.5696x; 1.3223x over previous
//
#include <hip/hip_runtime.h>
#include <stdint.h>

// LBG vector quantization, bit-faithful port of the JAX ref.
// Round 3: replace LDS-bin scatter with ballot-harvest GATHER (one block per
// (cluster, chunk)); flush = 64 u64 atomics/block instead of 16384.
// Sums quantization identical to R2 (round(x*2^20) per element, int64 total,
// <<20 at flush) => bit-identical trajectory; absmax should stay ~0.53.

#define NPTS 131072
#define DIMS 64
#define KCB  256

struct LbgState { float dist; float prev; unsigned int done; unsigned int k0, k1; unsigned int pad; };

__device__ __forceinline__ uint32_t rotl32(uint32_t v, int n){ return (v<<n)|(v>>(32-n)); }

// Threefry-2x32, 20 rounds (matches jax._src.prng.threefry2x32)
__device__ __forceinline__ void tf2x32(uint32_t k0, uint32_t k1, uint32_t x0, uint32_t x1,
                                       uint32_t& o0, uint32_t& o1){
  uint32_t ks2 = k0 ^ k1 ^ 0x1BD11BDAu;
  x0 += k0; x1 += k1;
  #define TFR(r) { x0 += x1; x1 = rotl32(x1, r); x1 ^= x0; }
  TFR(13) TFR(15) TFR(26) TFR(6)
  x0 += k1; x1 += ks2 + 1u;
  TFR(17) TFR(29) TFR(16) TFR(24)
  x0 += ks2; x1 += k0 + 2u;
  TFR(13) TFR(15) TFR(26) TFR(6)
  x0 += k0; x1 += k1 + 3u;
  TFR(17) TFR(29) TFR(16) TFR(24)
  x0 += k1; x1 += ks2 + 4u;
  TFR(13) TFR(15) TFR(26) TFR(6)
  x0 += ks2; x1 += k0 + 5u;
  #undef TFR
  o0 = x0; o1 = x1;
}

// XLA ErfInv (f32, Giles polynomial)
__device__ __forceinline__ float xla_erfinv_f32(float x){
  float w = -log1pf(-x*x);
  float p;
  if (w < 5.0f){
    w = w - 2.5f;
    p = 2.81022636e-08f;
    p = fmaf(p, w, 3.43273939e-07f);
    p = fmaf(p, w, -3.5233877e-06f);
    p = fmaf(p, w, -4.39150654e-06f);
    p = fmaf(p, w, 0.00021858087f);
    p = fmaf(p, w, -0.00125372503f);
    p = fmaf(p, w, -0.00417768164f);
    p = fmaf(p, w, 0.246640727f);
    p = fmaf(p, w, 1.50140941f);
  } else {
    w = sqrtf(w) - 3.0f;
    p = -0.000200214257f;
    p = fmaf(p, w, 0.000100950558f);
    p = fmaf(p, w, 0.00134934322f);
    p = fmaf(p, w, -0.00367342844f);
    p = fmaf(p, w, 0.00573950773f);
    p = fmaf(p, w, -0.0076224613f);
    p = fmaf(p, w, 0.00943887047f);
    p = fmaf(p, w, 1.00167406f);
    p = fmaf(p, w, 2.83297682f);
  }
  return p * x;
}

__device__ __forceinline__ float jax_normal_elem(uint32_t k0, uint32_t k1, uint32_t j){
  uint32_t o0, o1; tf2x32(k0, k1, 0u, j, o0, o1);
  uint32_t bits = o0 ^ o1;
  uint32_t fb = (bits >> 9) | 0x3f800000u;
  float f = __uint_as_float(fb) - 1.0f;
  const float lo = -0.99999994f;
  float u = f * 2.0f + lo;
  u = fmaxf(lo, u);
  return 1.41421356f * xla_erfinv_f32(u);
}

// --- mean of x (fixed-point 2^40 int64 atomics, deterministic) ---
__global__ void mean_kernel(const float* __restrict__ x, unsigned long long* __restrict__ macc){
  __shared__ double part[256];
  const int t = threadIdx.x;
  const int d = t & 63;
  const int w = t >> 6;
  const size_t base = (size_t)blockIdx.x * 1024;
  double s = 0.0;
  for (int j = w; j < 1024; j += 4)
    s += (double)x[(base + j) * DIMS + d];
  part[t] = s;
  __syncthreads();
  if (t < 64){
    double tot = part[t] + part[64+t] + part[128+t] + part[192+t];
    atomicAdd(&macc[t], (unsigned long long)__double2ll_rn(tot * 1099511627776.0));
  }
}

__global__ void init_kernel(float* __restrict__ cb, const unsigned long long* __restrict__ macc,
                            LbgState* __restrict__ st){
  const int t = threadIdx.x;
  for (int e = t; e < KCB*DIMS; e += 256){
    int c = e >> 6, d = e & 63;
    float v;
    if (c == 0){
      double mean = (double)(long long)macc[d] * (1.0/1099511627776.0) / 131072.0;
      v = (float)mean;
    } else v = 1e10f;
    cb[e] = v;
  }
  if (t == 0){
    st->dist = __builtin_inff();
    st->prev = __builtin_inff();
    st->done = 0u;
  }
}

// --- split level ---
__global__ void split_kernel(float* __restrict__ cb, float* __restrict__ cnorm,
                             unsigned long long* __restrict__ sums,
                             unsigned int* __restrict__ ndata,
                             unsigned long long* __restrict__ distacc,
                             LbgState* __restrict__ st, int curr, int split){
  __shared__ uint32_t kr0, kr1;
  const int t = threadIdx.x;
  if (t == 0){
    uint32_t ks0, ks1;
    tf2x32(0u, 42u, 0u, (uint32_t)split, ks0, ks1);
    uint32_t a0, a1, b0, b1;
    tf2x32(ks0, ks1, 0u, 0u, a0, a1);
    tf2x32(ks0, ks1, 0u, 1u, b0, b1);
    kr0 = a0; kr1 = a1;
    st->k0 = b0; st->k1 = b1;
    st->prev = st->dist;
    st->done = 0u;
  }
  __syncthreads();
  const int n = curr * DIMS;
  for (int e = t; e < n; e += 256){
    int c = e >> 6, d = e & 63;
    float rv = jax_normal_elem(kr0, kr1, (uint32_t)e) * 1e-5f;
    float old = cb[c*DIMS + d];
    cb[(curr + c)*DIMS + d] = old - rv;
    cb[c*DIMS + d]          = old + rv;
  }
  __syncthreads();
  const int c2 = curr * 2;
  for (int c = t; c < c2; c += 256){
    float s = 0.f;
    for (int d = 0; d < DIMS; d++){ float vv = cb[c*DIMS+d]; s += vv*vv; }
    cnorm[c] = s;
  }
  for (int e = t; e < c2*DIMS; e += 256) sums[e] = 0ull;
  for (int c = t; c < c2; c += 256) ndata[c] = 0u;
  if (t == 0) *distacc = 0ull;
}

// --- E-step: block = 64 points x 4 waves; wave w scans a uniform cw-slice. ---
template<int CURR>
__global__ __launch_bounds__(256, 4)
void estep_kernel(const float* __restrict__ x, const float* __restrict__ cb,
                  const float* __restrict__ cnorm, unsigned char* __restrict__ bidx8,
                  unsigned long long* __restrict__ distacc, const LbgState* __restrict__ st){
  if (st->done) return;
  constexpr int SPLITW = (CURR < 4) ? CURR : 4;
  constexpr int CW = CURR / SPLITW;            // codewords per wave
  __shared__ float sbest[SPLITW*64];
  __shared__ int   sidx [SPLITW*64];
  const int t = threadIdx.x;
  const int lane = t & 63;
  const int w = __builtin_amdgcn_readfirstlane(t >> 6);
  const int p = blockIdx.x * 64 + lane;

  float xv[DIMS];
  float xx = 0.f;
  if (w < SPLITW){
    const float4* xp = reinterpret_cast<const float4*>(x + (size_t)p * DIMS);
    #pragma unroll
    for (int i = 0; i < 16; i++){
      float4 v = xp[i];
      xv[4*i+0] = v.x; xv[4*i+1] = v.y; xv[4*i+2] = v.z; xv[4*i+3] = v.w;
    }
    #pragma unroll
    for (int d = 0; d < DIMS; d++) xx += xv[d] * xv[d];

    const int cbase = w * CW;
    constexpr int NJ = (CW < 4) ? CW : 4;
    float best = __builtin_inff();
    int bloc = 0;
    for (int j0 = 0; j0 < CW; j0 += NJ){
      const float* crow = cb + (size_t)(cbase + j0) * DIMS;
      float acc[NJ];
      #pragma unroll
      for (int k2 = 0; k2 < NJ; k2++) acc[k2] = 0.f;
      #pragma unroll
      for (int d = 0; d < DIMS; d++){
        #pragma unroll
        for (int k2 = 0; k2 < NJ; k2++)
          acc[k2] = fmaf(xv[d], crow[k2*DIMS + d], acc[k2]);
      }
      #pragma unroll
      for (int k2 = 0; k2 < NJ; k2++){
        float d2 = (xx - 2.0f*acc[k2]) + cnorm[cbase + j0 + k2];  // ref rounding order
        if (d2 < best){ best = d2; bloc = cbase + j0 + k2; }      // strict < = first-min
      }
    }
    sbest[w*64 + lane] = best;
    sidx [w*64 + lane] = bloc;
  }
  __syncthreads();
  if (w == 0){
    float best = sbest[lane];
    int bi = sidx[lane];
    #pragma unroll
    for (int ww = 1; ww < SPLITW; ww++){
      float ob = sbest[ww*64 + lane];
      int   oi = sidx [ww*64 + lane];
      if (ob < best){ best = ob; bi = oi; }   // ranges ascending -> ties keep lowest idx
    }
    bidx8[p] = (unsigned char)bi;
    // dist contribution: recompute sum((x-cb[bi])^2), same rounding as R1/R2
    double dd = 0.0;
    const float4* cbv = reinterpret_cast<const float4*>(cb + (size_t)bi * DIMS);
    #pragma unroll
    for (int i = 0; i < 16; i++){
      float4 b = cbv[i];
      float df, sq;
      df = xv[4*i+0] - b.x; sq = df*df; dd += (double)sq;
      df = xv[4*i+1] - b.y; sq = df*df; dd += (double)sq;
      df = xv[4*i+2] - b.z; sq = df*df; dd += (double)sq;
      df = xv[4*i+3] - b.w; sq = df*df; dd += (double)sq;
    }
    for (int off = 32; off > 0; off >>= 1) dd += __shfl_down(dd, off);
    if (lane == 0)
      atomicAdd(distacc, (unsigned long long)__double2ll_rn(dd * 4294967296.0));
  }
}

// --- Gather M-step accumulation: block (c, chunk); ballot-harvest matches,
// coalesced 64-lane row loads, per-lane int64 acc, 64 u64 atomics per block.
template<int CURR, int NBLK>
__global__ __launch_bounds__(256)
void gather_kernel(const float* __restrict__ x, const unsigned char* __restrict__ bidx8,
                   unsigned long long* __restrict__ sums, unsigned int* __restrict__ ndata,
                   const LbgState* __restrict__ st){
  if (st->done) return;
  constexpr int CLOG = __builtin_ctz(CURR);
  constexpr int NCHUNK = NBLK / CURR;
  constexpr int PPC = NPTS / NCHUNK;          // points per chunk
  constexpr int NPW = PPC / 4;                // points per wave (>=64, pow2)
  __shared__ long long sacc[4*64];
  __shared__ unsigned int scw[4];
  const int t = threadIdx.x;
  const int lane = t & 63;
  const int w = t >> 6;
  const int c = blockIdx.x & (CURR - 1);
  const int chunk = blockIdx.x >> CLOG;
  const int pbase = chunk * PPC + w * NPW;

  long long acc = 0;
  unsigned int cnt = 0;
  for (int i = 0; i < NPW; i += 64){
    const int pl = pbase + i + lane;
    const int b = (int)bidx8[pl];
    unsigned long long m = __ballot(b == c);
    cnt += (unsigned int)__popcll(m);
    while (m){
      const int bit = __builtin_ctzll(m);
      m &= m - 1ull;
      const int p = pbase + i + bit;
      const float v = x[(size_t)p * DIMS + lane];    // coalesced 256B row load
      acc += (long long)__double2int_rn((double)v * 1048576.0);
    }
  }
  sacc[w*64 + lane] = acc;
  if (lane == 0) scw[w] = cnt;
  __syncthreads();
  if (w == 0){
    long long tot = sacc[lane] + sacc[64+lane] + sacc[128+lane] + sacc[192+lane];
    if (tot) atomicAdd(&sums[c*DIMS + lane], (unsigned long long)(tot * 1048576ll)); // 2^20 -> 2^40
    if (lane == 0){
      unsigned int ct = scw[0] + scw[1] + scw[2] + scw[3];
      if (ct) atomicAdd(&ndata[c], ct);
    }
  }
}

// --- convergence + M-step finalize (one block) ---
__global__ void control_kernel(float* __restrict__ cb, float* __restrict__ cnorm,
                               unsigned long long* __restrict__ sums,
                               unsigned int* __restrict__ ndata,
                               unsigned long long* __restrict__ distacc,
                               LbgState* __restrict__ st, int curr, int n_iter){
  if (st->done) return;
  __shared__ int s_stop;
  __shared__ uint32_t sub0, sub1;
  __shared__ float cm[64];
  __shared__ int redv[256];
  __shared__ int redi[256];
  __shared__ int s_m, s_cnt;
  const int t = threadIdx.x;
  if (t == 0){
    double dd = (double)(long long)(*distacc) * (1.0/4294967296.0);
    float sf = (float)dd;
    float d_new = sf / 131072.0f;
    float change = fabsf(st->prev - d_new);
    int conv = (n_iter > 0) && (change / (d_new + 1e-16f) < 1e-5f);
    st->dist = d_new;
    if (!conv) st->prev = d_new;
    st->done = conv ? 1u : 0u;
    s_stop = conv;
    if (!conv){
      uint32_t a0, a1, b0, b1;
      tf2x32(st->k0, st->k1, 0u, 0u, a0, a1);
      tf2x32(st->k0, st->k1, 0u, 1u, b0, b1);
      st->k0 = a0; st->k1 = a1;
      sub0 = b0; sub1 = b1;
    }
  }
  __syncthreads();
  if (s_stop) return;

  int v = (t < curr) ? (int)ndata[t] : -1;
  redv[t] = v; redi[t] = t;
  __syncthreads();
  for (int s = 128; s > 0; s >>= 1){
    if (t < s){
      if (redv[t+s] > redv[t] || (redv[t+s] == redv[t] && redi[t+s] < redi[t])){
        redv[t] = redv[t+s]; redi[t] = redi[t+s];
      }
    }
    __syncthreads();
  }
  if (t == 0) s_m = redi[0];
  __syncthreads();
  redv[t] = (t < curr && ndata[t] == 0u) ? 1 : 0;
  __syncthreads();
  for (int s = 128; s > 0; s >>= 1){
    if (t < s) redv[t] += redv[t+s];
    __syncthreads();
  }
  if (t == 0) s_cnt = redv[0];
  __syncthreads();
  const int m = s_m;
  const int cntE = s_cnt;

  if (t < 64){
    unsigned int nm_ = ndata[m]; if (nm_ < 1u) nm_ = 1u;
    double cd = (double)(long long)sums[m*DIMS + t] * (1.0/1099511627776.0) / (double)nm_;
    cm[t] = (float)cd;
  }
  __syncthreads();

  const int total = curr * DIMS;
  for (int e = t; e < total; e += 256){
    int c = e >> 6, d = e & 63;
    if (c == m) continue;
    float nv;
    unsigned int nd = ndata[c];
    if (nd >= 1u){
      double cd = (double)(long long)sums[e] * (1.0/1099511627776.0) / (double)nd;
      nv = (float)cd;
    } else {
      float rv = jax_normal_elem(sub0, sub1, (uint32_t)e) * 1e-5f;
      nv = cm[d] - rv;
    }
    cb[e] = nv;
  }
  if (t < 64){
    float add = 0.f;
    if (cntE > 0){
      float acc = 0.f;
      for (int c = 0; c < curr; c++){
        if (ndata[c] == 0u)
          acc += jax_normal_elem(sub0, sub1, (uint32_t)(c*DIMS + t)) * 1e-5f;
      }
      add = acc / fmaxf((float)cntE, 1.0f);
    }
    cb[m*DIMS + t] = cm[t] + add;
  }
  __syncthreads();

  for (int c = t; c < curr; c += 256){
    float s = 0.f;
    for (int d = 0; d < DIMS; d++){ float vv = cb[c*DIMS+d]; s += vv*vv; }
    cnorm[c] = s;
  }
  for (int e = t; e < total; e += 256) sums[e] = 0ull;
  for (int c = t; c < curr; c += 256) ndata[c] = 0u;
  if (t == 0) *distacc = 0ull;
}

__global__ void finalize_kernel(float* __restrict__ out, const LbgState* __restrict__ st){
  out[KCB*DIMS] = st->dist;
}

extern "C" void kernel_launch(void* const* d_in, const int* in_sizes, int n_in,
                              void* d_out, int out_size, void* d_ws, size_t ws_size,
                              hipStream_t stream){
  const float* x = (const float*)d_in[0];
  float* out = (float*)d_out;
  float* cb = out;
  char* ws = (char*)d_ws;
  unsigned long long* sums    = (unsigned long long*)(ws + 0);       // 131072 B
  unsigned long long* macc    = (unsigned long long*)(ws + 131072);  // 512 B
  unsigned long long* distacc = (unsigned long long*)(ws + 131584);  // 8 B
  LbgState* st                = (LbgState*)(ws + 131592);            // 24 B
  unsigned int* ndata         = (unsigned int*)(ws + 131616);        // 1024 B
  float* cnorm                = (float*)(ws + 132640);               // 1024 B
  unsigned char* bidx8        = (unsigned char*)(ws + 133664);       // 131072 B -> 264736 total

  hipMemsetAsync(d_ws, 0, 264736, stream);
  mean_kernel<<<128, 256, 0, stream>>>(x, macc);
  init_kernel<<<1, 256, 0, stream>>>(cb, macc, st);

  int curr = 1;
  for (int split = 0; split < 8; split++){
    split_kernel<<<1, 256, 0, stream>>>(cb, cnorm, sums, ndata, distacc, st, curr, split);
    curr *= 2;
    for (int n = 0; n < 5; n++){
      switch (curr){
        case 2:   estep_kernel<2>  <<<2048,256,0,stream>>>(x,cb,cnorm,bidx8,distacc,st);
                  gather_kernel<2,512>   <<<512, 256,0,stream>>>(x,bidx8,sums,ndata,st); break;
        case 4:   estep_kernel<4>  <<<2048,256,0,stream>>>(x,cb,cnorm,bidx8,distacc,st);
                  gather_kernel<4,512>   <<<512, 256,0,stream>>>(x,bidx8,sums,ndata,st); break;
        case 8:   estep_kernel<8>  <<<2048,256,0,stream>>>(x,cb,cnorm,bidx8,distacc,st);
                  gather_kernel<8,512>   <<<512, 256,0,stream>>>(x,bidx8,sums,ndata,st); break;
        case 16:  estep_kernel<16> <<<2048,256,0,stream>>>(x,cb,cnorm,bidx8,distacc,st);
                  gather_kernel<16,512>  <<<512, 256,0,stream>>>(x,bidx8,sums,ndata,st); break;
        case 32:  estep_kernel<32> <<<2048,256,0,stream>>>(x,cb,cnorm,bidx8,distacc,st);
                  gather_kernel<32,512>  <<<512, 256,0,stream>>>(x,bidx8,sums,ndata,st); break;
        case 64:  estep_kernel<64> <<<2048,256,0,stream>>>(x,cb,cnorm,bidx8,distacc,st);
                  gather_kernel<64,512>  <<<512, 256,0,stream>>>(x,bidx8,sums,ndata,st); break;
        case 128: estep_kernel<128><<<2048,256,0,stream>>>(x,cb,cnorm,bidx8,distacc,st);
                  gather_kernel<128,1024><<<1024,256,0,stream>>>(x,bidx8,sums,ndata,st); break;
        case 256: estep_kernel<256><<<2048,256,0,stream>>>(x,cb,cnorm,bidx8,distacc,st);
                  gather_kernel<256,2048><<<2048,256,0,stream>>>(x,bidx8,sums,ndata,st); break;
      }
      control_kernel<<<1, 256, 0, stream>>>(cb, cnorm, sums, ndata, distacc, st, curr, n);
    }
  }
  finalize_kernel<<<1, 1, 0, stream>>>(out, st);
}